// Round 1
// baseline (686.408 us; speedup 1.0000x reference)
//
#include <hip/hip_runtime.h>

#define H    64
#define F    256
#define BM   64
#define NSEG 256

// ---------------------------------------------------------------------------
// Kernel 1: fused QKV projection.  q/k/v[n,j] = sum_i x[n,i]*W*[i,j] + b*[j]
// Block = 256 threads, handles BM=64 node rows.  x tile staged in LDS (64KB,
// 2 blocks/CU).  Thread (j = t&63, group mg = t>>6) computes 16 nodes x 3
// outputs = 48 accumulators.  W loads coalesced across j; LDS reads are
// wave-broadcast (conflict-free).
// ---------------------------------------------------------------------------
__global__ __launch_bounds__(256) void qkv_proj(
    const float* __restrict__ x,
    const float* __restrict__ Wq, const float* __restrict__ bq,
    const float* __restrict__ Wk, const float* __restrict__ bk,
    const float* __restrict__ Wv, const float* __restrict__ bv,
    float* __restrict__ q, float* __restrict__ k, float* __restrict__ v,
    int N)
{
    __shared__ float xs[BM][F];
    const int t = threadIdx.x;
    const int block0 = blockIdx.x * BM;
    const int rows = min(BM, N - block0);

    const float4* x4 = (const float4*)(x + (size_t)block0 * F);
    float4* xs4 = (float4*)&xs[0][0];
    #pragma unroll
    for (int it = 0; it < (BM * F / 4) / 256; ++it) {
        int idx = t + it * 256;
        int r = idx >> 6;                       // F/4 = 64 float4 per row
        float4 val = (r < rows) ? x4[idx] : make_float4(0.f, 0.f, 0.f, 0.f);
        xs4[idx] = val;
    }
    __syncthreads();

    const int j  = t & 63;
    const int m0 = (t >> 6) * 16;

    float aq[16], ak[16], av[16];
    const float bqj = bq[j], bkj = bk[j], bvj = bv[j];
    #pragma unroll
    for (int m = 0; m < 16; ++m) { aq[m] = bqj; ak[m] = bkj; av[m] = bvj; }

    for (int i = 0; i < F; i += 4) {
        float wq[4], wk[4], wv[4];
        #pragma unroll
        for (int u = 0; u < 4; ++u) {
            wq[u] = Wq[(i + u) * H + j];
            wk[u] = Wk[(i + u) * H + j];
            wv[u] = Wv[(i + u) * H + j];
        }
        #pragma unroll
        for (int m = 0; m < 16; ++m) {
            const float4 xv = *(const float4*)&xs[m0 + m][i];
            aq[m] += xv.x * wq[0] + xv.y * wq[1] + xv.z * wq[2] + xv.w * wq[3];
            ak[m] += xv.x * wk[0] + xv.y * wk[1] + xv.z * wk[2] + xv.w * wk[3];
            av[m] += xv.x * wv[0] + xv.y * wv[1] + xv.z * wv[2] + xv.w * wv[3];
        }
    }

    #pragma unroll
    for (int m = 0; m < 16; ++m) {
        int r = m0 + m;
        if (r < rows) {
            size_t o = (size_t)(block0 + r) * H + j;
            q[o] = aq[m]; k[o] = ak[m]; v[o] = av[m];
        }
    }
}

// ---------------------------------------------------------------------------
// Kernel 2: per-edge score.  One wave per edge, lane = feature.
//   p = dot(k[src], q[dest]) / 8 ;  ex = exp(p)
// exps[e] = ex;  LDS 256-entry segment histogram, one global atomic per
// segment per block at the end (grid-stride persistent blocks).
// ---------------------------------------------------------------------------
__global__ __launch_bounds__(256) void edge_score(
    const float* __restrict__ q, const float* __restrict__ k,
    const int* __restrict__ ei, const int* __restrict__ batch,
    float* __restrict__ exps, float* __restrict__ denom,
    int E, int N)
{
    __shared__ float sden[NSEG];
    sden[threadIdx.x] = 0.f;
    __syncthreads();

    const int lane = threadIdx.x & 63;
    const int nwaves = gridDim.x * 4;
    const int w = blockIdx.x * 4 + (threadIdx.x >> 6);

    for (int e = w; e < E; e += nwaves) {
        int src = ei[e];
        int dst = ei[E + e];
        src = min(max(src, 0), N - 1);
        dst = min(max(dst, 0), N - 1);
        float p = k[(size_t)src * H + lane] * q[(size_t)dst * H + lane];
        #pragma unroll
        for (int off = 32; off > 0; off >>= 1) p += __shfl_xor(p, off, 64);
        float ex = __expf(p * 0.125f);
        if (lane == 0) {
            exps[e] = ex;
            int seg = batch[src];
            seg = min(max(seg, 0), NSEG - 1);
            atomicAdd(&sden[seg], ex);
        }
    }
    __syncthreads();
    float d = sden[threadIdx.x];
    if (d != 0.f) atomicAdd(&denom[threadIdx.x], d);
}

// ---------------------------------------------------------------------------
// Kernel 3: normalize + scatter.  One wave per edge, lane = feature.
//   out[dest,:] += v[src,:] * exps[e] / (denom[seg]+1e-6)
// ---------------------------------------------------------------------------
__global__ __launch_bounds__(256) void edge_scatter(
    const float* __restrict__ v, const float* __restrict__ exps,
    const float* __restrict__ denom,
    const int* __restrict__ ei, const int* __restrict__ batch,
    float* __restrict__ out, int E, int N)
{
    const int e = (int)((blockIdx.x * 256 + threadIdx.x) >> 6);
    if (e >= E) return;
    const int lane = threadIdx.x & 63;
    int src = ei[e];
    int dst = ei[E + e];
    src = min(max(src, 0), N - 1);
    dst = min(max(dst, 0), N - 1);
    int seg = batch[src];
    seg = min(max(seg, 0), NSEG - 1);
    const float a = exps[e] / (denom[seg] + 1e-6f);
    atomicAdd(&out[(size_t)dst * H + lane], v[(size_t)src * H + lane] * a);
}

extern "C" void kernel_launch(void* const* d_in, const int* in_sizes, int n_in,
                              void* d_out, int out_size, void* d_ws, size_t ws_size,
                              hipStream_t stream)
{
    const float* x   = (const float*)d_in[0];
    const float* Wq  = (const float*)d_in[1];
    const float* bq  = (const float*)d_in[2];
    const float* Wk  = (const float*)d_in[3];
    const float* bk  = (const float*)d_in[4];
    const float* Wv  = (const float*)d_in[5];
    const float* bv  = (const float*)d_in[6];
    const int* ei    = (const int*)d_in[7];
    const int* batch = (const int*)d_in[8];

    const int N = in_sizes[8];        // 50000 nodes (batch has one entry per node)
    const int E = in_sizes[7] / 2;    // 800000 edges

    float* q     = (float*)d_ws;
    float* k     = q + (size_t)N * H;
    float* v     = k + (size_t)N * H;
    float* exps  = v + (size_t)N * H;
    float* denom = exps + E;          // 256 floats

    hipMemsetAsync(denom, 0, NSEG * sizeof(float), stream);
    hipMemsetAsync(d_out, 0, (size_t)out_size * sizeof(float), stream);

    qkv_proj<<<(N + BM - 1) / BM, 256, 0, stream>>>(
        x, Wq, bq, Wk, bk, Wv, bv, q, k, v, N);

    edge_score<<<768, 256, 0, stream>>>(q, k, ei, batch, exps, denom, E, N);

    edge_scatter<<<(E * 64 + 255) / 256, 256, 0, stream>>>(
        v, exps, denom, ei, batch, (float*)d_out, E, N);
}